// Round 4
// baseline (4495.564 us; speedup 1.0000x reference)
//
#include <hip/hip_runtime.h>
#include <hip/hip_bf16.h>

typedef __bf16 bf16;
typedef __bf16 bf16x8 __attribute__((ext_vector_type(8)));
typedef float floatx4 __attribute__((ext_vector_type(4)));
typedef float floatx16 __attribute__((ext_vector_type(16)));
typedef unsigned long long u64;

#define TSEQ 512
#define MFMA16 __builtin_amdgcn_mfma_f32_16x16x32_bf16

__device__ __forceinline__ float sigm(float x){ return 1.0f/(1.0f + __expf(-x)); }
__device__ __forceinline__ float tanh_fast(float x){
    float e = __expf(2.0f*x);
    return 1.0f - 2.0f/(e + 1.0f);   // correct limits at +-inf
}

// fp32 -> bf16 converter
__global__ __launch_bounds__(256, 4)
void f2b_kernel(const float* __restrict__ in, bf16* __restrict__ out, int n)
{
    int i = blockIdx.x*256 + threadIdx.x;
    if (i < n) out[i] = (bf16)in[i];
}

// ---------------------------------------------------------------------------
// Pack Whh (1024 x 256 fp32) into MFMA-16x16x32 B-frag-major bf16 layout:
// Wp[ntile 0..63][kstep 0..7][lane 0..63][e 0..7], value =
//   Whh[gatecol = ntile*16 + (lane&15)][k = kstep*32 + (lane>>4)*8 + e]
// ---------------------------------------------------------------------------
__global__ __launch_bounds__(256, 4)
void pack_whh(const float* __restrict__ whh, bf16* __restrict__ wp)
{
    int idx = blockIdx.x*256 + threadIdx.x;
    if (idx >= 32768) return;
    int lane = idx & 63, ks = (idx >> 6) & 7, nt = idx >> 9;
    int row = nt*16 + (lane & 15);
    int k0  = ks*32 + (lane >> 4)*8;
    const float* src = whh + (size_t)row*256 + k0;
    bf16x8 v;
    #pragma unroll
    for (int e = 0; e < 8; e++) v[e] = (bf16)src[e];
    ((bf16x8*)wp)[idx] = v;
}

// ---------------------------------------------------------------------------
// xg = x @ Wih^T + bias for one 256-step chunk, both dirs (blockIdx.z).
// Output natural layout: xg[dir][seq 0..63][sloc 0..255][1024] fp32.
// ---------------------------------------------------------------------------
template<int DIN, bool XF32>
__global__ __launch_bounds__(256, 2)
void xg_gemm(const void* __restrict__ xin,
             const bf16* __restrict__ wbf, const bf16* __restrict__ wbb,
             const float* __restrict__ bf_, const float* __restrict__ bb_,
             float* __restrict__ xg, int chunk)
{
    __shared__ char smem[64*144*2];
    const int tid = threadIdx.x;
    const int wv = tid >> 6, ln = tid & 63;
    const int mi = wv & 1, ni = wv >> 1;
    const int l31 = ln & 31, lh = ln >> 5;
    char* At = smem;
    char* Bt = smem + 64*144;

    const int d   = blockIdx.z;
    const int seq = blockIdx.x >> 2;
    const int tb  = blockIdx.x & 3;
    const int n0  = blockIdx.y * 64;
    const bf16*  wb   = d ? wbb : wbf;
    const float* bias = d ? bb_ : bf_;
    const int sl0 = tb*64;
    const int t0  = d ? (511 - (chunk*256 + sl0)) : (chunk*256 + sl0);
    const int stp = d ? -1 : 1;

    floatx16 acc;
    #pragma unroll
    for (int r = 0; r < 16; r++) acc[r] = 0.0f;

    for (int kc = 0; kc < DIN; kc += 64) {
        __syncthreads();
        for (int c = tid; c < 1024; c += 256) {
            const int which = c >> 9, idx = c & 511;
            const int row = idx >> 3, k8 = idx & 7;
            if (which == 0) {
                const int trow = t0 + row*stp;
                if constexpr (XF32) {
                    const float* src = (const float*)xin
                        + ((size_t)seq*TSEQ + trow)*DIN + kc + k8*8;
                    const float4 lo = *(const float4*)src;
                    const float4 hi = *(const float4*)(src+4);
                    bf16 tmp[8] = {(bf16)lo.x,(bf16)lo.y,(bf16)lo.z,(bf16)lo.w,
                                   (bf16)hi.x,(bf16)hi.y,(bf16)hi.z,(bf16)hi.w};
                    *(uint4*)(At + row*144 + k8*16) = *(uint4*)tmp;
                } else {
                    const bf16* src = (const bf16*)xin
                        + ((size_t)seq*TSEQ + trow)*DIN + kc + k8*8;
                    *(uint4*)(At + row*144 + k8*16) = *(const uint4*)src;
                }
            } else {
                *(uint4*)(Bt + row*144 + k8*16) =
                    *(const uint4*)(wb + (size_t)(n0+row)*DIN + kc + k8*8);
            }
        }
        __syncthreads();
        #pragma unroll
        for (int ks = 0; ks < 4; ks++) {
            bf16x8 a = *(const bf16x8*)(At + (mi*32 + l31)*144 + ks*32 + lh*16);
            bf16x8 b = *(const bf16x8*)(Bt + (ni*32 + l31)*144 + ks*32 + lh*16);
            acc = __builtin_amdgcn_mfma_f32_32x32x16_bf16(a, b, acc, 0, 0, 0);
        }
    }
    const int col = n0 + ni*32 + l31;
    const float bv = bias[col];
    #pragma unroll
    for (int r = 0; r < 16; r++) {
        const int rowl = mi*32 + (r&3) + 8*(r>>2) + 4*lh;
        const int sloc = sl0 + rowl;
        xg[((size_t)(d*64 + seq)*256 + sloc)*1024 + col] = acc[r] + bv;
    }
}

// ---------------------------------------------------------------------------
// Hidden-split recurrence: 32 blocks = 4 hsplit x 2 dir x 4 bg; 512 thr
// (8 waves, 2/SIMD). Each block: 16 seqs x 64 h-cols, K = full 256.
// blk = hs*8 + d*4 + bg. Waves 0-3 (gp0): gates i,f for col-quarter cc=w;
// waves 4-7 (gp1): gates g,o. ALL Whh B-frags register-resident (64 VGPR/wave).
// Per step: 16 MFMA/wave -> (g,o) accs to LDS -> barrier -> gp0 full cell math
// + own-half h store (LDS + hsout + xh payload + per-wave flag) while gp1
// polls partner flags and sc0/sc1-loads 3 partner halves into next h buffer.
// xh parity-double-buffered; flags monotonic (sbase) -> skew <= 1 step, safe.
// ---------------------------------------------------------------------------
__global__ __launch_bounds__(512, 1)
void rec_kernel(const float* __restrict__ xg,
                const bf16* __restrict__ WpF, const bf16* __restrict__ WpB,
                bf16* __restrict__ hsout, float* __restrict__ cst,
                u64* __restrict__ xh, unsigned int* __restrict__ flg,
                int chunk, int sbase)
{
    __shared__ char hbuf[2][16*528];          // h_prev dbuf, 528B row stride
    __shared__ float exch[4][2][16][17];      // (g,o) gate exchange, padded

    const int tid = threadIdx.x;
    const int w = tid >> 6, l = tid & 63;
    const int l15 = l & 15, lq = l >> 4;
    const int blk = blockIdx.x;
    const int hs = blk >> 3, g8 = blk & 7;
    const int d = g8 >> 2, bg = g8 & 3;
    const int gp = w >> 2, cc = w & 3;
    const bf16x8* Wp = (const bf16x8*)(d ? WpB : WpF);

    // B-frags fully in registers: ntiles (2gp)*16 + hs*4 + cc and +16
    const int nt0 = (2*gp)*16 + hs*4 + cc;
    bf16x8 WB0[8], WB1[8];
    #pragma unroll
    for (int ks = 0; ks < 8; ks++) {
        WB0[ks] = Wp[nt0*512 + ks*64 + l];
        WB1[ks] = Wp[(nt0+16)*512 + ks*64 + l];
    }

    // h buffer init
    if (chunk == 0) {
        for (int i = tid; i < 4224; i += 512) ((unsigned int*)hbuf)[i] = 0u;
    } else {
        const int tprev = d ? (512 - chunk*256) : (chunk*256 - 1);
        const int row = tid >> 5, c8 = (tid & 31)*8;
        uint4 v = *(const uint4*)(hsout
            + ((size_t)(bg*16+row)*TSEQ + tprev)*512 + d*256 + c8);
        *(uint4*)(&hbuf[0][row*528 + c8*2]) = v;
    }

    // c-state (gp0 threads own 4 cells: rows lq*4+r, col hs*64+cc*16+l15)
    float cs[4];
    if (gp == 0) {
        if (chunk == 0) { cs[0]=cs[1]=cs[2]=cs[3]=0.0f; }
        else {
            float4 cv = ((const float4*)cst)[blk*256 + tid];
            cs[0]=cv.x; cs[1]=cv.y; cs[2]=cv.z; cs[3]=cv.w;
        }
    } else { cs[0]=cs[1]=cs[2]=cs[3]=0.0f; }

    // xg addressing (C-in; bias already folded in)
    const int colg0 = (2*gp)*256 + hs*64 + cc*16 + l15;
    const int colg1 = colg0 + 256;
    const float* xgb = xg + (size_t)(d*64 + bg*16)*256*1024;
    size_t ro[4];
    #pragma unroll
    for (int r = 0; r < 4; r++) ro[r] = (size_t)(lq*4 + r)*256*1024;
    float xn0[4], xn1[4];
    #pragma unroll
    for (int r = 0; r < 4; r++) {
        xn0[r] = xgb[ro[r] + colg0];
        xn1[r] = xgb[ro[r] + colg1];
    }

    // partner flag index per lane (gp1 poll): lanes 0..11 -> 3 partners x 4 waves
    const int pp = l >> 2;
    const int fidx = ((((hs + 1 + pp) & 3)*8 + g8) << 2) | (l & 3);

    __syncthreads();
    const int aoffb = l15*528 + lq*16;

    for (int sl = 0; sl < 256; ++sl) {
        const int s = chunk*256 + sl;
        const int t = d ? (511 - s) : s;
        const char* hr = hbuf[sl & 1];
        char* hw = hbuf[(sl+1) & 1];
        const int par = sl & 1;

        // ---- MFMA phase: gates = xg + h_prev @ Whh^T (B all in regs) ----
        floatx4 a0, a1;
        #pragma unroll
        for (int r = 0; r < 4; r++) { a0[r] = xn0[r]; a1[r] = xn1[r]; }
        bf16x8 Ac = *(const bf16x8*)(hr + aoffb);
        #pragma unroll
        for (int ks = 0; ks < 8; ks++) {
            bf16x8 An = Ac;
            if (ks < 7) An = *(const bf16x8*)(hr + aoffb + (ks+1)*64);
            a0 = MFMA16(Ac, WB0[ks], a0, 0,0,0);
            a1 = MFMA16(Ac, WB1[ks], a1, 0,0,0);
            Ac = An;
        }
        // prefetch next step's xg C-in (consumed after 2 barriers -> covered)
        if (sl < 255) {
            const size_t xo = (size_t)(sl+1)*1024;
            #pragma unroll
            for (int r = 0; r < 4; r++) {
                xn0[r] = xgb[ro[r] + xo + colg0];
                xn1[r] = xgb[ro[r] + xo + colg1];
            }
        }
        // gp1 exposes (g,o) accs
        if (gp == 1) {
            #pragma unroll
            for (int r = 0; r < 4; r++) {
                exch[cc][0][lq*4+r][l15] = a0[r];
                exch[cc][1][lq*4+r][l15] = a1[r];
            }
        }
        __syncthreads();

        if (gp == 0) {
            // ---- full cell math (i,f own; g,o from LDS) ----
            const int colh = hs*64 + cc*16 + l15;
            union { u64 q; bf16 hh[4]; } pk;
            #pragma unroll
            for (int r = 0; r < 4; r++) {
                const float gI = a0[r], gF = a1[r];
                const float gG = exch[cc][0][lq*4+r][l15];
                const float gO = exch[cc][1][lq*4+r][l15];
                const float cn = sigm(gF)*cs[r] + sigm(gI)*tanh_fast(gG);
                cs[r] = cn;
                const bf16 hb_ = (bf16)(sigm(gO)*tanh_fast(cn));
                pk.hh[r] = hb_;
                hsout[((size_t)(bg*16 + lq*4 + r)*TSEQ + t)*512 + d*256 + colh] = hb_;
            }
            if (sl < 255) {
                #pragma unroll
                for (int r = 0; r < 4; r++)
                    *(bf16*)(hw + (lq*4+r)*528 + colh*2) = pk.hh[r];
                __hip_atomic_store(&xh[par*8192 + blk*256 + (cc*16+l15)*4 + lq],
                                   pk.q, __ATOMIC_RELAXED, __HIP_MEMORY_SCOPE_AGENT);
                asm volatile("s_waitcnt vmcnt(0)" ::: "memory");
                if (l == 0)
                    __hip_atomic_store(&flg[blk*4 + w], (unsigned int)(sbase+sl+1),
                                       __ATOMIC_RELAXED, __HIP_MEMORY_SCOPE_AGENT);
            }
        } else if (sl < 255) {
            // ---- fetch 3 partner h-halves for next step ----
            const unsigned int tgt = (unsigned int)(sbase + sl + 1);
            unsigned int f = tgt;
            for (;;) {
                if (l < 12)
                    f = __hip_atomic_load(&flg[fidx], __ATOMIC_RELAXED,
                                          __HIP_MEMORY_SCOPE_AGENT);
                if (__all(f >= tgt)) break;
                __builtin_amdgcn_s_sleep(1);
            }
            const int cl = (cc*16 + l15)*4 + lq;
            const u64* p0 = xh + par*8192 + (((hs+1)&3)*8 + g8)*256 + cl;
            const u64* p1 = xh + par*8192 + (((hs+2)&3)*8 + g8)*256 + cl;
            const u64* p2 = xh + par*8192 + (((hs+3)&3)*8 + g8)*256 + cl;
            u64 q0, q1, q2;
            asm volatile(
                "global_load_dwordx2 %0, %3, off sc0 sc1\n\t"
                "global_load_dwordx2 %1, %4, off sc0 sc1\n\t"
                "global_load_dwordx2 %2, %5, off sc0 sc1\n\t"
                "s_waitcnt vmcnt(0)"
                : "=&v"(q0), "=&v"(q1), "=&v"(q2)
                : "v"((const void*)p0), "v"((const void*)p1), "v"((const void*)p2)
                : "memory");
            union { u64 q; bf16 hh[4]; } u0, u1, u2;
            u0.q = q0; u1.q = q1; u2.q = q2;
            const int c0 = ((hs+1)&3)*64 + cc*16 + l15;
            const int c1 = ((hs+2)&3)*64 + cc*16 + l15;
            const int c2 = ((hs+3)&3)*64 + cc*16 + l15;
            #pragma unroll
            for (int r = 0; r < 4; r++) {
                *(bf16*)(hw + (lq*4+r)*528 + c0*2) = u0.hh[r];
                *(bf16*)(hw + (lq*4+r)*528 + c1*2) = u1.hh[r];
                *(bf16*)(hw + (lq*4+r)*528 + c2*2) = u2.hh[r];
            }
        }
        __syncthreads();
    }

    if (gp == 0)
        ((float4*)cst)[blk*256 + tid] = make_float4(cs[0], cs[1], cs[2], cs[3]);
}

// ---------------------------------------------------------------------------
// Shared 64x64 bf16 GEMM main loop (attention chain) — unchanged.
// ---------------------------------------------------------------------------
__device__ __forceinline__ floatx16 gemm_loop(const bf16* __restrict__ A0,
                                              const bf16* __restrict__ Bt0,
                                              int lda, int ldb, int K, int brows,
                                              char* smem)
{
    const int tid = threadIdx.x;
    const int wave = tid >> 6, lane = tid & 63;
    const int mi = wave & 1, ni = wave >> 1;
    const int l31 = lane & 31, lh = lane >> 5;
    char* At = smem;
    char* Bt = smem + 64*144;
    floatx16 acc;
    #pragma unroll
    for (int r = 0; r < 16; r++) acc[r] = 0.0f;

    for (int kc = 0; kc < K; kc += 64) {
        __syncthreads();
        for (int c = tid; c < 1024; c += 256) {
            int which = c >> 9;
            int idx = c & 511;
            int row = idx >> 3, kch = idx & 7;
            uint4 v;
            if (which == 0) {
                v = *(const uint4*)(A0 + (size_t)row*lda + kc + kch*8);
                *(uint4*)(At + row*144 + kch*16) = v;
            } else {
                if (row < brows) v = *(const uint4*)(Bt0 + (size_t)row*ldb + kc + kch*8);
                else             v = make_uint4(0,0,0,0);
                *(uint4*)(Bt + row*144 + kch*16) = v;
            }
        }
        __syncthreads();
        #pragma unroll
        for (int ks = 0; ks < 4; ks++) {
            bf16x8 a = *(const bf16x8*)(At + (mi*32 + l31)*144 + ks*32 + lh*16);
            bf16x8 b = *(const bf16x8*)(Bt + (ni*32 + l31)*144 + ks*32 + lh*16);
            acc = __builtin_amdgcn_mfma_f32_32x32x16_bf16(a, b, acc, 0, 0, 0);
        }
    }
    return acc;
}

__global__ __launch_bounds__(256, 2)
void sgemm_scores(const bf16* __restrict__ hs1, float* __restrict__ S)
{
    __shared__ char smem[64*144*2];
    int n = blockIdx.z, tm = blockIdx.x, tn = blockIdx.y;
    const bf16* base = hs1 + (size_t)n*512*512;
    floatx16 acc = gemm_loop(base + (size_t)tm*64*512, base + (size_t)tn*64*512,
                             512, 512, 512, 64, smem);
    int wave = threadIdx.x >> 6, lane = threadIdx.x & 63;
    int mi = wave & 1, ni = wave >> 1;
    #pragma unroll
    for (int r = 0; r < 16; r++) {
        int row = tm*64 + mi*32 + (r&3) + 8*(r>>2) + 4*(lane>>5);
        int col = tn*64 + ni*32 + (lane&31);
        S[(size_t)n*512*512 + (size_t)row*512 + col] = acc[r];
    }
}

__global__ __launch_bounds__(256, 4)
void softmax_rows(const float* __restrict__ S, bf16* __restrict__ P)
{
    int row = blockIdx.x*4 + (threadIdx.x >> 6);
    int lane = threadIdx.x & 63;
    const float* src = S + (size_t)row*512 + lane*8;
    float4 a = *(const float4*)(src);
    float4 b = *(const float4*)(src + 4);
    float v[8] = {a.x,a.y,a.z,a.w,b.x,b.y,b.z,b.w};
    float m = v[0];
    #pragma unroll
    for (int j = 1; j < 8; j++) m = fmaxf(m, v[j]);
    #pragma unroll
    for (int off = 32; off > 0; off >>= 1) m = fmaxf(m, __shfl_xor(m, off));
    float s = 0.0f;
    #pragma unroll
    for (int j = 0; j < 8; j++) { v[j] = __expf(v[j]-m); s += v[j]; }
    #pragma unroll
    for (int off = 32; off > 0; off >>= 1) s += __shfl_xor(s, off);
    float inv = 1.0f/s;
    union { uint4 u; bf16 h[8]; } pk;
    #pragma unroll
    for (int j = 0; j < 8; j++) pk.h[j] = (bf16)(v[j]*inv);
    *(uint4*)(P + (size_t)row*512 + lane*8) = pk.u;
}

__global__ __launch_bounds__(256, 2)
void transpose_nt(const bf16* __restrict__ hs1, bf16* __restrict__ hs1T)
{
    __shared__ bf16 tile[64][72];
    int n = blockIdx.z, tX = blockIdx.x, fX = blockIdx.y;
    const bf16* src = hs1 + (size_t)n*512*512;
    for (int c = threadIdx.x; c < 512; c += 256) {
        int row = c >> 3, kch = c & 7;
        *(uint4*)(&tile[row][kch*8]) =
            *(const uint4*)(src + (size_t)(tX*64+row)*512 + fX*64 + kch*8);
    }
    __syncthreads();
    bf16* dst = hs1T + (size_t)n*512*512;
    for (int c = threadIdx.x; c < 512; c += 256) {
        int frow = c >> 3, tch = c & 7;
        bf16 tmp[8];
        #pragma unroll
        for (int j = 0; j < 8; j++) tmp[j] = tile[tch*8+j][frow];
        *(uint4*)(dst + (size_t)(fX*64+frow)*512 + tX*64 + tch*8) = *(uint4*)tmp;
    }
}

__global__ __launch_bounds__(256, 2)
void ctx_gemm(const bf16* __restrict__ P, const bf16* __restrict__ hs1T,
              bf16* __restrict__ ctx)
{
    __shared__ char smem[64*144*2];
    int n = blockIdx.z, tm = blockIdx.x, tn = blockIdx.y;
    const bf16* A0 = P    + (size_t)n*512*512 + (size_t)tm*64*512;
    const bf16* B0 = hs1T + (size_t)n*512*512 + (size_t)tn*64*512;
    floatx16 acc = gemm_loop(A0, B0, 512, 512, 512, 64, smem);
    int wave = threadIdx.x >> 6, lane = threadIdx.x & 63;
    int mi = wave & 1, ni = wave >> 1;
    #pragma unroll
    for (int r = 0; r < 16; r++) {
        int row = tm*64 + mi*32 + (r&3) + 8*(r>>2) + 4*(lane>>5);
        int col = tn*64 + ni*32 + (lane&31);
        ctx[((size_t)n*512 + row)*512 + col] = (bf16)acc[r];
    }
}

__global__ __launch_bounds__(256, 2)
void fc1_gemm(const bf16* __restrict__ ctx, const bf16* __restrict__ hs1,
              const bf16* __restrict__ wb, const float* __restrict__ b,
              float* __restrict__ outp)
{
    __shared__ char smem[64*144*2];
    const int tid = threadIdx.x;
    const int wave = tid >> 6, lane = tid & 63;
    const int mi = wave & 1, ni = wave >> 1;
    const int l31 = lane & 31, lh = lane >> 5;
    char* At = smem;
    char* Bt = smem + 64*144;
    const int m0 = blockIdx.x*64;
    floatx16 acc;
    #pragma unroll
    for (int r = 0; r < 16; r++) acc[r] = 0.0f;

    for (int kc = 0; kc < 1024; kc += 64) {
        const bf16* Asrc = (kc < 512) ? ctx : hs1;
        const int koff = kc & 511;
        __syncthreads();
        for (int c = tid; c < 1024; c += 256) {
            int which = c >> 9, idx = c & 511;
            int row = idx >> 3, kch = idx & 7;
            uint4 v;
            if (which == 0) {
                v = *(const uint4*)(Asrc + (size_t)(m0+row)*512 + koff + kch*8);
                *(uint4*)(At + row*144 + kch*16) = v;
            } else {
                if (row < 50) v = *(const uint4*)(wb + (size_t)row*1024 + kc + kch*8);
                else          v = make_uint4(0,0,0,0);
                *(uint4*)(Bt + row*144 + kch*16) = v;
            }
        }
        __syncthreads();
        #pragma unroll
        for (int ks = 0; ks < 4; ks++) {
            bf16x8 a = *(const bf16x8*)(At + (mi*32 + l31)*144 + ks*32 + lh*16);
            bf16x8 bb = *(const bf16x8*)(Bt + (ni*32 + l31)*144 + ks*32 + lh*16);
            acc = __builtin_amdgcn_mfma_f32_32x32x16_bf16(a, bb, acc, 0, 0, 0);
        }
    }
    #pragma unroll
    for (int r = 0; r < 16; r++) {
        int row = m0 + mi*32 + (r&3) + 8*(r>>2) + 4*lh;
        int col = ni*32 + l31;
        if (col < 50) {
            float v = acc[r] + b[col];
            outp[(size_t)row*50 + col] = fmaxf(v, 0.0f);
        }
    }
}

__global__ __launch_bounds__(256, 4)
void bn_stats(const float* __restrict__ fc1out, float* __restrict__ stats)
{
    __shared__ float sh[512];
    int c = blockIdx.x;
    float s = 0.0f, ss = 0.0f;
    for (int i = threadIdx.x; i < 32768; i += 256) {
        int n = i >> 9, q = i & 511;
        float x = fc1out[(size_t)n*25600 + c*512 + q];
        s += x; ss += x*x;
    }
    sh[threadIdx.x] = s; sh[256 + threadIdx.x] = ss;
    __syncthreads();
    for (int o = 128; o > 0; o >>= 1) {
        if (threadIdx.x < o) {
            sh[threadIdx.x] += sh[threadIdx.x + o];
            sh[256+threadIdx.x] += sh[256+threadIdx.x + o];
        }
        __syncthreads();
    }
    if (threadIdx.x == 0) {
        float mean = sh[0] / 32768.0f;
        float var  = sh[256] / 32768.0f - mean*mean;
        stats[c]      = mean;
        stats[64 + c] = rsqrtf(var + 1e-5f);
    }
}

__global__ __launch_bounds__(256, 4)
void tail_kernel(const float* __restrict__ fc1out, const float* __restrict__ stats,
                 const float* __restrict__ bng, const float* __restrict__ bnb,
                 const float* __restrict__ fc2w, const float* __restrict__ fc2b,
                 const float* __restrict__ fc3w, const float* __restrict__ fc3b,
                 const float* __restrict__ fc4w, const float* __restrict__ fc4b,
                 float* __restrict__ outp)
{
    __shared__ float W2[1250], W3[250], B2[25], B3[10], W4[20], B4[2];
    __shared__ float G[50], Bb[50], MU[50], IS[50];
    for (int i = threadIdx.x; i < 1250; i += 256) W2[i] = fc2w[i];
    for (int i = threadIdx.x; i < 250;  i += 256) W3[i] = fc3w[i];
    if (threadIdx.x < 25) B2[threadIdx.x] = fc2b[threadIdx.x];
    if (threadIdx.x < 20) W4[threadIdx.x] = fc4w[threadIdx.x];
    if (threadIdx.x < 10) B3[threadIdx.x] = fc3b[threadIdx.x];
    if (threadIdx.x < 2)  B4[threadIdx.x] = fc4b[threadIdx.x];
    if (threadIdx.x < 50) {
        G[threadIdx.x]  = bng[threadIdx.x];
        Bb[threadIdx.x] = bnb[threadIdx.x];
        MU[threadIdx.x] = stats[threadIdx.x];
        IS[threadIdx.x] = stats[64 + threadIdx.x];
    }
    __syncthreads();
    int m = blockIdx.x*256 + threadIdx.x;
    int t = m & 511;
    const float* src = fc1out + (size_t)m*50;
    float x[50];
    #pragma unroll
    for (int c = 0; c < 50; c++) {
        int j = (t*50 + c) >> 9;
        x[c] = (src[c] - MU[j])*IS[j]*G[j] + Bb[j];
    }
    float y2[25];
    #pragma unroll
    for (int o = 0; o < 25; o++) {
        float a = B2[o];
        for (int c = 0; c < 50; c++) a += x[c]*W2[o*50+c];
        y2[o] = fmaxf(a, 0.0f);
    }
    float y3[10];
    #pragma unroll
    for (int o = 0; o < 10; o++) {
        float a = B3[o];
        for (int c = 0; c < 25; c++) a += y2[c]*W3[o*25+c];
        y3[o] = fmaxf(a, 0.0f);
    }
    #pragma unroll
    for (int o = 0; o < 2; o++) {
        float a = B4[o];
        for (int c = 0; c < 10; c++) a += y3[c]*W4[o*10+c];
        outp[(size_t)m*2 + o] = a;
    }
}

extern "C" void kernel_launch(void* const* d_in, const int* in_sizes, int n_in,
                              void* d_out, int out_size, void* d_ws, size_t ws_size,
                              hipStream_t stream)
{
    const float* x       = (const float*)d_in[0];
    const float* wih_l0f = (const float*)d_in[1];
    const float* whh_l0f = (const float*)d_in[2];
    const float* b_l0f   = (const float*)d_in[3];
    const float* wih_l0b = (const float*)d_in[4];
    const float* whh_l0b = (const float*)d_in[5];
    const float* b_l0b   = (const float*)d_in[6];
    const float* wih_l1f = (const float*)d_in[7];
    const float* whh_l1f = (const float*)d_in[8];
    const float* b_l1f   = (const float*)d_in[9];
    const float* wih_l1b = (const float*)d_in[10];
    const float* whh_l1b = (const float*)d_in[11];
    const float* b_l1b   = (const float*)d_in[12];
    const float* fc1w    = (const float*)d_in[13];
    const float* fc1b    = (const float*)d_in[14];
    const float* bng     = (const float*)d_in[15];
    const float* bnb     = (const float*)d_in[16];
    const float* fc2w    = (const float*)d_in[17];
    const float* fc2b    = (const float*)d_in[18];
    const float* fc3w    = (const float*)d_in[19];
    const float* fc3b    = (const float*)d_in[20];
    const float* fc4w    = (const float*)d_in[21];
    const float* fc4b    = (const float*)d_in[22];

    // ---- workspace layout ----
    char* ws = (char*)d_ws;
    float* stats  = (float*)ws;                        // 512 B
    unsigned int* flg = (unsigned int*)(ws + 1024);    // 128 u32 (memset/launch)
    bf16*  fc1wb  = (bf16*)(ws + 4096);                // 102400 B
    bf16*  hs0    = (bf16*)(ws + 131072);              // 32 MiB
    bf16*  hs1    = (bf16*)(ws + 33685504);            // 32 MiB
    float* xg     = (float*)(ws + 67239936);           // 128 MiB (one chunk)
    bf16*  wb0f   = (bf16*)(ws + 201457664);           // 256 KiB
    bf16*  wb0b   = (bf16*)(ws + 201719808);           // 256 KiB
    bf16*  wb1f   = (bf16*)(ws + 201981952);           // 1 MiB
    bf16*  wb1b   = (bf16*)(ws + 203030528);           // 1 MiB
    bf16*  Wp0f   = (bf16*)(ws + 204079104);           // 512 KiB
    bf16*  Wp0b   = (bf16*)(ws + 204603392);           // 512 KiB
    bf16*  Wp1f   = (bf16*)(ws + 205127680);           // 512 KiB
    bf16*  Wp1b   = (bf16*)(ws + 205651968);           // 512 KiB
    float* cst    = (float*)(ws + 206176256);          // 128 KiB
    u64*   xh     = (u64*)(ws + 206307328);            // 128 KiB (parity dbuf)
    // post-rec overlays (xg / weight packs dead by then):
    bf16*  ctx    = (bf16*)(ws + 67239936);            // 32 MiB
    float* S      = (float*)(ws + 100794368);          // 64 MiB
    bf16*  P      = (bf16*)(ws + 167903232);           // 32 MiB
    float* fc1out = (float*)(ws + 201457664);          // 6.25 MiB
    bf16*  hs1T   = (bf16*)S;

    // flags must be zero each launch (graph re-execution safety)
    hipMemsetAsync(d_ws, 0, 4096, stream);

    // ---- weight prep ----
    f2b_kernel<<<200, 256, 0, stream>>>(fc1w, fc1wb, 51200);
    f2b_kernel<<<512, 256, 0, stream>>>(wih_l0f, wb0f, 131072);
    f2b_kernel<<<512, 256, 0, stream>>>(wih_l0b, wb0b, 131072);
    f2b_kernel<<<2048, 256, 0, stream>>>(wih_l1f, wb1f, 524288);
    f2b_kernel<<<2048, 256, 0, stream>>>(wih_l1b, wb1b, 524288);
    pack_whh<<<128, 256, 0, stream>>>(whh_l0f, Wp0f);
    pack_whh<<<128, 256, 0, stream>>>(whh_l0b, Wp0b);
    pack_whh<<<128, 256, 0, stream>>>(whh_l1f, Wp1f);
    pack_whh<<<128, 256, 0, stream>>>(whh_l1b, Wp1b);

    dim3 gxg(256, 16, 2);
    // ---- layer 0 ----
    xg_gemm<128, true><<<gxg, 256, 0, stream>>>(x, wb0f, wb0b, b_l0f, b_l0b, xg, 0);
    rec_kernel<<<32, 512, 0, stream>>>(xg, Wp0f, Wp0b, hs0, cst, xh, flg, 0, 0);
    xg_gemm<128, true><<<gxg, 256, 0, stream>>>(x, wb0f, wb0b, b_l0f, b_l0b, xg, 1);
    rec_kernel<<<32, 512, 0, stream>>>(xg, Wp0f, Wp0b, hs0, cst, xh, flg, 1, 256);
    // ---- layer 1 ----
    xg_gemm<512, false><<<gxg, 256, 0, stream>>>(hs0, wb1f, wb1b, b_l1f, b_l1b, xg, 0);
    rec_kernel<<<32, 512, 0, stream>>>(xg, Wp1f, Wp1b, hs1, cst, xh, flg, 0, 512);
    xg_gemm<512, false><<<gxg, 256, 0, stream>>>(hs0, wb1f, wb1b, b_l1f, b_l1b, xg, 1);
    rec_kernel<<<32, 512, 0, stream>>>(xg, Wp1f, Wp1b, hs1, cst, xh, flg, 1, 768);

    // ---- attention + head ----
    dim3 g88(8, 8, 64);
    sgemm_scores<<<g88, 256, 0, stream>>>(hs1, S);
    softmax_rows<<<8192, 256, 0, stream>>>(S, P);
    transpose_nt<<<g88, 256, 0, stream>>>(hs1, hs1T);
    ctx_gemm<<<g88, 256, 0, stream>>>(P, hs1T, ctx);
    fc1_gemm<<<512, 256, 0, stream>>>(ctx, hs1, fc1wb, fc1b, fc1out);
    bn_stats<<<50, 256, 0, stream>>>(fc1out, stats);
    tail_kernel<<<128, 256, 0, stream>>>(fc1out, stats, bng, bnb, fc2w, fc2b,
                                         fc3w, fc3b, fc4w, fc4b, (float*)d_out);
    (void)in_sizes; (void)n_in; (void)out_size; (void)ws_size;
}